// Round 1
// baseline (626.305 us; speedup 1.0000x reference)
//
#include <hip/hip_runtime.h>
#include <hip/hip_bf16.h>
#include <stdint.h>

typedef _Float16 half8 __attribute__((ext_vector_type(8)));
typedef _Float16 half4v __attribute__((ext_vector_type(4)));
typedef float f32x4 __attribute__((ext_vector_type(4)));

#define T_STEPS 20
#define B_SZ 512
#define D_IN 4096
#define H_SZ 1024
#define C_SZ 100
#define M_TOT (T_STEPS * B_SZ)  // 10240
#define BK 32

// ---------- helpers ----------
__device__ __forceinline__ void gload16(const _Float16* g, _Float16* l) {
  __builtin_amdgcn_global_load_lds(
      (const __attribute__((address_space(1))) void*)g,
      (__attribute__((address_space(3))) void*)l, 16, 0, 0);
}

// ---------- prep: fp32 -> (hi,lo) fp16 split, 4 elems/thread ----------
__global__ void k_split4(const float* __restrict__ x, _Float16* __restrict__ hi,
                         _Float16* __restrict__ lo) {
  int64_t i = (int64_t)blockIdx.x * blockDim.x + threadIdx.x;
  float4 v = ((const float4* __restrict__)x)[i];
  half4v h, l;
  h.x = (_Float16)v.x; l.x = (_Float16)(v.x - (float)h.x);
  h.y = (_Float16)v.y; l.y = (_Float16)(v.y - (float)h.y);
  h.z = (_Float16)v.z; l.z = (_Float16)(v.z - (float)h.z);
  h.w = (_Float16)v.w; l.w = (_Float16)(v.w - (float)h.w);
  ((half4v*)hi)[i] = h;
  ((half4v*)lo)[i] = l;
}

// W2 [100][1024] -> padded [112][1024] hi/lo (pad rows zero)
__global__ void k_prep_w2(const float* __restrict__ w2, _Float16* __restrict__ hi,
                          _Float16* __restrict__ lo) {
  int i = blockIdx.x * 256 + threadIdx.x;  // 0 .. 112*1024-1
  float v = (i < C_SZ * H_SZ) ? w2[i] : 0.0f;
  _Float16 h = (_Float16)v;
  hi[i] = h;
  lo[i] = (_Float16)(v - (float)h);
}

// ---------- big GEMM: Hbuf[M_TOT][H_SZ] = A[M_TOT][D_IN] * W^T, 3-term fp16 split ----------
__global__ __launch_bounds__(256) void k_gemm1(
    const _Float16* __restrict__ Ahi, const _Float16* __restrict__ Alo,
    const _Float16* __restrict__ Whi, const _Float16* __restrict__ Wlo,
    float* __restrict__ Hbuf) {
  __shared__ _Float16 sAh[128 * BK];
  __shared__ _Float16 sAl[128 * BK];
  __shared__ _Float16 sWh[128 * BK];
  __shared__ _Float16 sWl[128 * BK];

  const int tid = threadIdx.x;
  const int64_t m0 = (int64_t)blockIdx.y * 128;
  const int64_t n0 = (int64_t)blockIdx.x * 128;

  // staging map: slot = iss*256 + tid; row = slot>>2; col = (slot&3)*8; lds half-off = slot*8
  const int srow = tid >> 2;
  const int scol = (tid & 3) * 8;
  const _Float16* gAh = Ahi + (m0 + srow) * D_IN + scol;
  const _Float16* gAl = Alo + (m0 + srow) * D_IN + scol;
  const _Float16* gWh = Whi + (n0 + srow) * D_IN + scol;
  const _Float16* gWl = Wlo + (n0 + srow) * D_IN + scol;
  const int ls = tid * 8;
  const int64_t g2 = (int64_t)64 * D_IN;  // second issue: +64 rows

  const int lane = tid & 63;
  const int wid = tid >> 6;
  const int wm = (wid >> 1) * 64;
  const int wn = (wid & 1) * 64;
  const int fr = lane & 15;
  const int quad = lane >> 4;

  f32x4 acc[4][4] = {};

  for (int kt = 0; kt < D_IN; kt += BK) {
    __syncthreads();
    gload16(gAh + kt, &sAh[ls]);
    gload16(gAh + kt + g2, &sAh[ls + 2048]);
    gload16(gAl + kt, &sAl[ls]);
    gload16(gAl + kt + g2, &sAl[ls + 2048]);
    gload16(gWh + kt, &sWh[ls]);
    gload16(gWh + kt + g2, &sWh[ls + 2048]);
    gload16(gWl + kt, &sWl[ls]);
    gload16(gWl + kt + g2, &sWl[ls + 2048]);
    __syncthreads();

    half8 ah[4], al[4], bh[4], bl[4];
#pragma unroll
    for (int i = 0; i < 4; ++i) {
      const int ro = (wm + i * 16 + fr) * BK + quad * 8;
      ah[i] = *(const half8*)&sAh[ro];
      al[i] = *(const half8*)&sAl[ro];
    }
#pragma unroll
    for (int j = 0; j < 4; ++j) {
      const int ro = (wn + j * 16 + fr) * BK + quad * 8;
      bh[j] = *(const half8*)&sWh[ro];
      bl[j] = *(const half8*)&sWl[ro];
    }
#pragma unroll
    for (int i = 0; i < 4; ++i) {
#pragma unroll
      for (int j = 0; j < 4; ++j) {
        acc[i][j] = __builtin_amdgcn_mfma_f32_16x16x32_f16(ah[i], bh[j], acc[i][j], 0, 0, 0);
        acc[i][j] = __builtin_amdgcn_mfma_f32_16x16x32_f16(ah[i], bl[j], acc[i][j], 0, 0, 0);
        acc[i][j] = __builtin_amdgcn_mfma_f32_16x16x32_f16(al[i], bh[j], acc[i][j], 0, 0, 0);
      }
    }
  }

  // epilogue: C/D layout col=lane&15, row=quad*4+reg
#pragma unroll
  for (int i = 0; i < 4; ++i) {
#pragma unroll
    for (int r = 0; r < 4; ++r) {
      const int64_t row = m0 + wm + i * 16 + quad * 4 + r;
      float* dst = Hbuf + row * H_SZ + n0 + wn + fr;
#pragma unroll
      for (int j = 0; j < 4; ++j) dst[j * 16] = acc[i][j][r];
    }
  }
}

// ---------- BN stats: per (t,h) column over B rows -> scale/shift ----------
__global__ void k_stats(const float* __restrict__ Hbuf, const float* __restrict__ gamma,
                        float* __restrict__ scale, float* __restrict__ shift) {
  const int t = blockIdx.y;
  const int n = blockIdx.x * 256 + threadIdx.x;
  const float* p = Hbuf + (int64_t)t * B_SZ * H_SZ + n;
  float s = 0.f, s2 = 0.f;
  for (int b = 0; b < B_SZ; ++b) {
    float v = p[(int64_t)b * H_SZ];
    s += v;
    s2 += v * v;
  }
  const float mean = s * (1.0f / B_SZ);
  const float var = s2 * (1.0f / B_SZ) - mean * mean;
  const float rs = rsqrtf(var + 1e-4f);
  const float sc = gamma[t * H_SZ + n] * rs;
  scale[t * H_SZ + n] = sc;
  shift[t * H_SZ + n] = -mean * sc;
}

// ---------- LIF recurrence per (b,h): spike count S ----------
__global__ void k_recur(const float* __restrict__ Hbuf, const float* __restrict__ scale,
                        const float* __restrict__ shift, _Float16* __restrict__ S) {
  const int idx = blockIdx.x * 256 + threadIdx.x;  // 0..512*1024-1
  const int b = idx >> 10;
  const int h = idx & 1023;
  float mem = 0.f;
  int cnt = 0;
#pragma unroll
  for (int t = 0; t < T_STEPS; ++t) {
    float v = Hbuf[((int64_t)(t * B_SZ + b) << 10) + h];
    v = v * scale[(t << 10) + h] + shift[(t << 10) + h];
    mem = 0.95f * mem + v;
    if (mem - 1.0f > 0.0f) {
      ++cnt;
      mem -= 1.0f;
    }
  }
  S[idx] = (_Float16)cnt;
}

// ---------- GEMM2: out = S @ W2^T / 20, 2-term fp16 split ----------
__global__ void k_gemm2(const _Float16* __restrict__ S, const _Float16* __restrict__ W2h,
                        const _Float16* __restrict__ W2l, float* __restrict__ out) {
  const int wid = threadIdx.x >> 6;
  const int lane = threadIdx.x & 63;
  const int m0 = blockIdx.y * 64 + wid * 16;
  const int n0 = blockIdx.x * 16;
  const int fr = lane & 15;
  const int quad = lane >> 4;

  const _Float16* sp = S + (int64_t)(m0 + fr) * H_SZ + quad * 8;
  const _Float16* wph = W2h + (int64_t)(n0 + fr) * H_SZ + quad * 8;
  const _Float16* wpl = W2l + (int64_t)(n0 + fr) * H_SZ + quad * 8;

  f32x4 acc = {0.f, 0.f, 0.f, 0.f};
#pragma unroll 4
  for (int k = 0; k < H_SZ; k += 32) {
    half8 a = *(const half8*)(sp + k);
    half8 bh = *(const half8*)(wph + k);
    half8 bl = *(const half8*)(wpl + k);
    acc = __builtin_amdgcn_mfma_f32_16x16x32_f16(a, bh, acc, 0, 0, 0);
    acc = __builtin_amdgcn_mfma_f32_16x16x32_f16(a, bl, acc, 0, 0, 0);
  }
  const int col = n0 + fr;
  if (col < C_SZ) {
#pragma unroll
    for (int r = 0; r < 4; ++r) {
      const int row = m0 + quad * 4 + r;
      out[row * C_SZ + col] = acc[r] * (1.0f / T_STEPS);
    }
  }
}

extern "C" void kernel_launch(void* const* d_in, const int* in_sizes, int n_in,
                              void* d_out, int out_size, void* d_ws, size_t ws_size,
                              hipStream_t stream) {
  const float* z = (const float*)d_in[0];      // [20,512,4096]
  const float* W1 = (const float*)d_in[1];     // [1024,4096]
  const float* gamma = (const float*)d_in[2];  // [20,1024]
  const float* W2 = (const float*)d_in[3];     // [100,1024]
  float* out = (float*)d_out;                  // [512,100]

  char* ws = (char*)d_ws;
  size_t off = 0;
  auto alloc = [&](size_t bytes) -> void* {
    void* p = ws + off;
    off += (bytes + 255) & ~(size_t)255;
    return p;
  };
  _Float16* Ahi = (_Float16*)alloc((size_t)M_TOT * D_IN * 2);
  _Float16* Alo = (_Float16*)alloc((size_t)M_TOT * D_IN * 2);
  _Float16* Whi = (_Float16*)alloc((size_t)H_SZ * D_IN * 2);
  _Float16* Wlo = (_Float16*)alloc((size_t)H_SZ * D_IN * 2);
  float* Hbuf = (float*)alloc((size_t)M_TOT * H_SZ * 4);
  float* scale = (float*)alloc((size_t)T_STEPS * H_SZ * 4);
  float* shift = (float*)alloc((size_t)T_STEPS * H_SZ * 4);
  _Float16* S = (_Float16*)alloc((size_t)B_SZ * H_SZ * 2);
  _Float16* W2h = (_Float16*)alloc((size_t)112 * H_SZ * 2);
  _Float16* W2l = (_Float16*)alloc((size_t)112 * H_SZ * 2);

  // 1) split z and W1 into fp16 hi/lo planes
  k_split4<<<(M_TOT * (int64_t)D_IN) / 1024, 256, 0, stream>>>(z, Ahi, Alo);
  k_split4<<<(H_SZ * D_IN) / 1024, 256, 0, stream>>>(W1, Whi, Wlo);
  k_prep_w2<<<(112 * H_SZ) / 256, 256, 0, stream>>>(W2, W2h, W2l);

  // 2) batched fc1 GEMM for all 20 timesteps
  dim3 g1(H_SZ / 128, M_TOT / 128);  // (8, 80)
  k_gemm1<<<g1, 256, 0, stream>>>(Ahi, Alo, Whi, Wlo, Hbuf);

  // 3) BN stats
  dim3 gs(H_SZ / 256, T_STEPS);  // (4, 20)
  k_stats<<<gs, 256, 0, stream>>>(Hbuf, gamma, scale, shift);

  // 4) LIF recurrence -> spike counts
  k_recur<<<(B_SZ * H_SZ) / 256, 256, 0, stream>>>(Hbuf, scale, shift, S);

  // 5) spike-count GEMM -> output
  dim3 g2(7, 8);  // n-tiles of 16 (112 cols padded), m-tiles of 64
  k_gemm2<<<g2, 256, 0, stream>>>(S, W2h, W2l, out);
}

// Round 2
// 577.315 us; speedup vs baseline: 1.0849x; 1.0849x over previous
//
#include <hip/hip_runtime.h>
#include <hip/hip_bf16.h>
#include <stdint.h>

typedef _Float16 half8 __attribute__((ext_vector_type(8)));
typedef _Float16 half4v __attribute__((ext_vector_type(4)));
typedef float f32x4 __attribute__((ext_vector_type(4)));

#define T_STEPS 20
#define B_SZ 512
#define D_IN 4096
#define H_SZ 1024
#define C_SZ 100
#define M_TOT (T_STEPS * B_SZ)  // 10240
#define BK 32

// ---------- helpers ----------
__device__ __forceinline__ void gload16(const _Float16* g, _Float16* l) {
  __builtin_amdgcn_global_load_lds(
      (const __attribute__((address_space(1))) void*)g,
      (__attribute__((address_space(3))) void*)l, 16, 0, 0);
}

// ---------- prep: fp32 -> (hi,lo) fp16 split, 4 elems/thread ----------
__global__ void k_split4(const float* __restrict__ x, _Float16* __restrict__ hi,
                         _Float16* __restrict__ lo) {
  int64_t i = (int64_t)blockIdx.x * blockDim.x + threadIdx.x;
  float4 v = ((const float4* __restrict__)x)[i];
  half4v h, l;
  h.x = (_Float16)v.x; l.x = (_Float16)(v.x - (float)h.x);
  h.y = (_Float16)v.y; l.y = (_Float16)(v.y - (float)h.y);
  h.z = (_Float16)v.z; l.z = (_Float16)(v.z - (float)h.z);
  h.w = (_Float16)v.w; l.w = (_Float16)(v.w - (float)h.w);
  ((half4v*)hi)[i] = h;
  ((half4v*)lo)[i] = l;
}

// W2 [100][1024] -> padded [112][1024] hi/lo (pad rows zero)
__global__ void k_prep_w2(const float* __restrict__ w2, _Float16* __restrict__ hi,
                          _Float16* __restrict__ lo) {
  int i = blockIdx.x * 256 + threadIdx.x;  // 0 .. 112*1024-1
  float v = (i < C_SZ * H_SZ) ? w2[i] : 0.0f;
  _Float16 h = (_Float16)v;
  hi[i] = h;
  lo[i] = (_Float16)(v - (float)h);
}

// ---------- big GEMM: Hbuf[M_TOT][H_SZ] = A[M_TOT][D_IN] * W^T, 3-term fp16 split ----------
// XCD-aware swizzle: hardware round-robins consecutive blockIdx across the 8
// XCDs. Give each XCD an exclusive band of 10 m-tiles and run all 8 n-tiles of
// a given m-tile on the SAME XCD, so the A-tile is fetched into that XCD's L2
// once and reused 8x (R1 counter evidence: FETCH_SIZE 957 MB vs 184 MB ideal,
// gemm1 HBM-bound at 3.1 TB/s).
__global__ __launch_bounds__(256) void k_gemm1(
    const _Float16* __restrict__ Ahi, const _Float16* __restrict__ Alo,
    const _Float16* __restrict__ Whi, const _Float16* __restrict__ Wlo,
    float* __restrict__ Hbuf) {
  __shared__ _Float16 sAh[128 * BK];
  __shared__ _Float16 sAl[128 * BK];
  __shared__ _Float16 sWh[128 * BK];
  __shared__ _Float16 sWl[128 * BK];

  const int tid = threadIdx.x;
  const int bid = blockIdx.x;          // 0..639
  const int xcd = bid & 7;             // HW round-robin XCD id
  const int q = bid >> 3;              // 0..79 within this XCD
  const int mt = xcd * 10 + (q >> 3);  // 10 m-tiles per XCD
  const int nt = q & 7;                // all 8 n-tiles stay on this XCD
  const int64_t m0 = (int64_t)mt * 128;
  const int64_t n0 = (int64_t)nt * 128;

  // staging map: slot = iss*256 + tid; row = slot>>2; col = (slot&3)*8; lds half-off = slot*8
  const int srow = tid >> 2;
  const int scol = (tid & 3) * 8;
  const _Float16* gAh = Ahi + (m0 + srow) * D_IN + scol;
  const _Float16* gAl = Alo + (m0 + srow) * D_IN + scol;
  const _Float16* gWh = Whi + (n0 + srow) * D_IN + scol;
  const _Float16* gWl = Wlo + (n0 + srow) * D_IN + scol;
  const int ls = tid * 8;
  const int64_t g2 = (int64_t)64 * D_IN;  // second issue: +64 rows

  const int lane = tid & 63;
  const int wid = tid >> 6;
  const int wm = (wid >> 1) * 64;
  const int wn = (wid & 1) * 64;
  const int fr = lane & 15;
  const int quad = lane >> 4;

  f32x4 acc[4][4] = {};

  for (int kt = 0; kt < D_IN; kt += BK) {
    __syncthreads();
    gload16(gAh + kt, &sAh[ls]);
    gload16(gAh + kt + g2, &sAh[ls + 2048]);
    gload16(gAl + kt, &sAl[ls]);
    gload16(gAl + kt + g2, &sAl[ls + 2048]);
    gload16(gWh + kt, &sWh[ls]);
    gload16(gWh + kt + g2, &sWh[ls + 2048]);
    gload16(gWl + kt, &sWl[ls]);
    gload16(gWl + kt + g2, &sWl[ls + 2048]);
    __syncthreads();

    half8 ah[4], al[4], bh[4], bl[4];
#pragma unroll
    for (int i = 0; i < 4; ++i) {
      const int ro = (wm + i * 16 + fr) * BK + quad * 8;
      ah[i] = *(const half8*)&sAh[ro];
      al[i] = *(const half8*)&sAl[ro];
    }
#pragma unroll
    for (int j = 0; j < 4; ++j) {
      const int ro = (wn + j * 16 + fr) * BK + quad * 8;
      bh[j] = *(const half8*)&sWh[ro];
      bl[j] = *(const half8*)&sWl[ro];
    }
#pragma unroll
    for (int i = 0; i < 4; ++i) {
#pragma unroll
      for (int j = 0; j < 4; ++j) {
        acc[i][j] = __builtin_amdgcn_mfma_f32_16x16x32_f16(ah[i], bh[j], acc[i][j], 0, 0, 0);
        acc[i][j] = __builtin_amdgcn_mfma_f32_16x16x32_f16(ah[i], bl[j], acc[i][j], 0, 0, 0);
        acc[i][j] = __builtin_amdgcn_mfma_f32_16x16x32_f16(al[i], bh[j], acc[i][j], 0, 0, 0);
      }
    }
  }

  // epilogue: C/D layout col=lane&15, row=quad*4+reg
#pragma unroll
  for (int i = 0; i < 4; ++i) {
#pragma unroll
    for (int r = 0; r < 4; ++r) {
      const int64_t row = m0 + wm + i * 16 + quad * 4 + r;
      float* dst = Hbuf + row * H_SZ + n0 + wn + fr;
#pragma unroll
      for (int j = 0; j < 4; ++j) dst[j * 16] = acc[i][j][r];
    }
  }
}

// ---------- BN stats: per (t,h) column over B rows -> scale/shift ----------
__global__ void k_stats(const float* __restrict__ Hbuf, const float* __restrict__ gamma,
                        float* __restrict__ scale, float* __restrict__ shift) {
  const int t = blockIdx.y;
  const int n = blockIdx.x * 256 + threadIdx.x;
  const float* p = Hbuf + (int64_t)t * B_SZ * H_SZ + n;
  float s = 0.f, s2 = 0.f;
  for (int b = 0; b < B_SZ; ++b) {
    float v = p[(int64_t)b * H_SZ];
    s += v;
    s2 += v * v;
  }
  const float mean = s * (1.0f / B_SZ);
  const float var = s2 * (1.0f / B_SZ) - mean * mean;
  const float rs = rsqrtf(var + 1e-4f);
  const float sc = gamma[t * H_SZ + n] * rs;
  scale[t * H_SZ + n] = sc;
  shift[t * H_SZ + n] = -mean * sc;
}

// ---------- LIF recurrence per (b,h): spike count S ----------
__global__ void k_recur(const float* __restrict__ Hbuf, const float* __restrict__ scale,
                        const float* __restrict__ shift, _Float16* __restrict__ S) {
  const int idx = blockIdx.x * 256 + threadIdx.x;  // 0..512*1024-1
  const int b = idx >> 10;
  const int h = idx & 1023;
  float mem = 0.f;
  int cnt = 0;
#pragma unroll
  for (int t = 0; t < T_STEPS; ++t) {
    float v = Hbuf[((int64_t)(t * B_SZ + b) << 10) + h];
    v = v * scale[(t << 10) + h] + shift[(t << 10) + h];
    mem = 0.95f * mem + v;
    if (mem - 1.0f > 0.0f) {
      ++cnt;
      mem -= 1.0f;
    }
  }
  S[idx] = (_Float16)cnt;
}

// ---------- GEMM2: out = S @ W2^T / 20, 2-term fp16 split ----------
__global__ void k_gemm2(const _Float16* __restrict__ S, const _Float16* __restrict__ W2h,
                        const _Float16* __restrict__ W2l, float* __restrict__ out) {
  const int wid = threadIdx.x >> 6;
  const int lane = threadIdx.x & 63;
  const int m0 = blockIdx.y * 64 + wid * 16;
  const int n0 = blockIdx.x * 16;
  const int fr = lane & 15;
  const int quad = lane >> 4;

  const _Float16* sp = S + (int64_t)(m0 + fr) * H_SZ + quad * 8;
  const _Float16* wph = W2h + (int64_t)(n0 + fr) * H_SZ + quad * 8;
  const _Float16* wpl = W2l + (int64_t)(n0 + fr) * H_SZ + quad * 8;

  f32x4 acc = {0.f, 0.f, 0.f, 0.f};
#pragma unroll 4
  for (int k = 0; k < H_SZ; k += 32) {
    half8 a = *(const half8*)(sp + k);
    half8 bh = *(const half8*)(wph + k);
    half8 bl = *(const half8*)(wpl + k);
    acc = __builtin_amdgcn_mfma_f32_16x16x32_f16(a, bh, acc, 0, 0, 0);
    acc = __builtin_amdgcn_mfma_f32_16x16x32_f16(a, bl, acc, 0, 0, 0);
  }
  const int col = n0 + fr;
  if (col < C_SZ) {
#pragma unroll
    for (int r = 0; r < 4; ++r) {
      const int row = m0 + quad * 4 + r;
      out[row * C_SZ + col] = acc[r] * (1.0f / T_STEPS);
    }
  }
}

extern "C" void kernel_launch(void* const* d_in, const int* in_sizes, int n_in,
                              void* d_out, int out_size, void* d_ws, size_t ws_size,
                              hipStream_t stream) {
  const float* z = (const float*)d_in[0];      // [20,512,4096]
  const float* W1 = (const float*)d_in[1];     // [1024,4096]
  const float* gamma = (const float*)d_in[2];  // [20,1024]
  const float* W2 = (const float*)d_in[3];     // [100,1024]
  float* out = (float*)d_out;                  // [512,100]

  char* ws = (char*)d_ws;
  size_t off = 0;
  auto alloc = [&](size_t bytes) -> void* {
    void* p = ws + off;
    off += (bytes + 255) & ~(size_t)255;
    return p;
  };
  _Float16* Ahi = (_Float16*)alloc((size_t)M_TOT * D_IN * 2);
  _Float16* Alo = (_Float16*)alloc((size_t)M_TOT * D_IN * 2);
  _Float16* Whi = (_Float16*)alloc((size_t)H_SZ * D_IN * 2);
  _Float16* Wlo = (_Float16*)alloc((size_t)H_SZ * D_IN * 2);
  float* Hbuf = (float*)alloc((size_t)M_TOT * H_SZ * 4);
  float* scale = (float*)alloc((size_t)T_STEPS * H_SZ * 4);
  float* shift = (float*)alloc((size_t)T_STEPS * H_SZ * 4);
  _Float16* S = (_Float16*)alloc((size_t)B_SZ * H_SZ * 2);
  _Float16* W2h = (_Float16*)alloc((size_t)112 * H_SZ * 2);
  _Float16* W2l = (_Float16*)alloc((size_t)112 * H_SZ * 2);

  // 1) split z and W1 into fp16 hi/lo planes
  k_split4<<<(M_TOT * (int64_t)D_IN) / 1024, 256, 0, stream>>>(z, Ahi, Alo);
  k_split4<<<(H_SZ * D_IN) / 1024, 256, 0, stream>>>(W1, Whi, Wlo);
  k_prep_w2<<<(112 * H_SZ) / 256, 256, 0, stream>>>(W2, W2h, W2l);

  // 2) batched fc1 GEMM for all 20 timesteps (1-D grid, XCD swizzle inside)
  k_gemm1<<<640, 256, 0, stream>>>(Ahi, Alo, Whi, Wlo, Hbuf);

  // 3) BN stats
  dim3 gs(H_SZ / 256, T_STEPS);  // (4, 20)
  k_stats<<<gs, 256, 0, stream>>>(Hbuf, gamma, scale, shift);

  // 4) LIF recurrence -> spike counts
  k_recur<<<(B_SZ * H_SZ) / 256, 256, 0, stream>>>(Hbuf, scale, shift, S);

  // 5) spike-count GEMM -> output
  dim3 g2(7, 8);  // n-tiles of 16 (112 cols padded), m-tiles of 64
  k_gemm2<<<g2, 256, 0, stream>>>(S, W2h, W2l, out);
}